// Round 14
// baseline (7407.239 us; speedup 1.0000x reference)
//
#include <hip/hip_runtime.h>
#include <hip/hip_bf16.h>
#include <stdint.h>

typedef short bf16x8 __attribute__((ext_vector_type(8)));
typedef float f32x4  __attribute__((ext_vector_type(4)));
typedef unsigned int u32x4 __attribute__((ext_vector_type(4)));
typedef unsigned int u32x2 __attribute__((ext_vector_type(2)));

static __device__ __forceinline__ unsigned short bf16_rne(float f) {
    unsigned u = __builtin_bit_cast(unsigned, f);
    unsigned r = u + 0x7fffu + ((u >> 16) & 1u);
    return (unsigned short)(r >> 16);
}
static __device__ __forceinline__ float bf16tof(unsigned short h) {
    unsigned u = ((unsigned)h) << 16;
    return __builtin_bit_cast(float, u);
}

// ---------------- K1: transpose + convert W_xh [K][N] f32 -> Wt [N][K] bf16 ---
__global__ __launch_bounds__(256) void k_transpose(const float* __restrict__ W,
                                                   unsigned short* __restrict__ Wt) {
    __shared__ float tile[64][65];
    int bx = blockIdx.x & 15, by = blockIdx.x >> 4;
    int n0 = bx * 64, k0 = by * 64;
    int tx = threadIdx.x & 63, ty = threadIdx.x >> 6;
#pragma unroll
    for (int p = 0; p < 16; ++p) {
        int r = p * 4 + ty;
        tile[r][tx] = W[(size_t)(k0 + r) * 1024 + n0 + tx];
    }
    __syncthreads();
#pragma unroll
    for (int p = 0; p < 16; ++p) {
        int r = p * 4 + ty;
        Wt[(size_t)(n0 + r) * 1024 + k0 + tx] = bf16_rne(tile[tx][r]);
    }
}

// ---------------- K2: Xp = X @ W_xh + b_h  (bf16 MFMA, 128x128x32 tiles) ------
#define LDA 80

__global__ __launch_bounds__(256) void k_xpgemm(const float* __restrict__ X,
                                                const unsigned short* __restrict__ Wt,
                                                const float* __restrict__ bh,
                                                unsigned short* __restrict__ Xp) {
    __shared__ __align__(16) unsigned char ldsA[128 * LDA];
    __shared__ __align__(16) unsigned char ldsB[128 * LDA];
    int p = blockIdx.x;
    int lo = (p & 7) * 256 + (p >> 3);
    int mt = lo >> 3, nt = lo & 7;
    int m0 = mt * 128, n0 = nt * 128;
    int tid = threadIdx.x;
    int lane = tid & 63, wid = tid >> 6;
    int wr = wid >> 1, wc = wid & 1;
    int mw = wr * 64, nw = wc * 64;
    int l15 = lane & 15, kg = lane >> 4;

    f32x4 acc[4][4] = {};
    int arow = tid >> 3, as = tid & 7;
    int brow = tid >> 2, bs = tid & 3;

    for (int kt = 0; kt < 32; ++kt) {
#pragma unroll
        for (int pp = 0; pp < 4; ++pp) {
            int r = pp * 32 + arow;
            const float4 v = *(const float4*)(X + (size_t)(m0 + r) * 1024 + kt * 32 + as * 4);
            unsigned lo32 = ((unsigned)bf16_rne(v.y) << 16) | bf16_rne(v.x);
            unsigned hi32 = ((unsigned)bf16_rne(v.w) << 16) | bf16_rne(v.z);
            *(uint2*)(ldsA + r * LDA + as * 8) = make_uint2(lo32, hi32);
        }
#pragma unroll
        for (int pp = 0; pp < 2; ++pp) {
            int r = pp * 64 + brow;
            uint4 v = *(const uint4*)(Wt + (size_t)(n0 + r) * 1024 + kt * 32 + bs * 8);
            *(uint4*)(ldsB + r * LDA + bs * 16) = v;
        }
        __syncthreads();
        bf16x8 af[4];
#pragma unroll
        for (int i = 0; i < 4; ++i)
            af[i] = *(const bf16x8*)(ldsA + (mw + 16 * i + l15) * LDA + kg * 16);
#pragma unroll
        for (int j = 0; j < 4; ++j) {
            bf16x8 bfj = *(const bf16x8*)(ldsB + (nw + 16 * j + l15) * LDA + kg * 16);
#pragma unroll
            for (int i = 0; i < 4; ++i)
                acc[i][j] = __builtin_amdgcn_mfma_f32_16x16x32_bf16(af[i], bfj, acc[i][j], 0, 0, 0);
        }
        __syncthreads();
    }
#pragma unroll
    for (int j = 0; j < 4; ++j) {
        int col = n0 + nw + 16 * j + l15;
        float bias = bh[col];
#pragma unroll
        for (int i = 0; i < 4; ++i) {
            int rb = m0 + mw + 16 * i + kg * 4;
#pragma unroll
            for (int r = 0; r < 4; ++r)
                Xp[(size_t)(rb + r) * 1024 + col] = bf16_rne(acc[i][j][r] + bias);
        }
    }
}

// ---------------- K3: interleaved scan. 2 sets x 8 WGs, C=2 chains/set. -------
#define SB0 __builtin_amdgcn_sched_barrier(0)
#define WV0 asm volatile("s_waitcnt vmcnt(0)" ::: "memory")
#define WLG0 asm volatile("s_waitcnt lgkmcnt(0)" ::: "memory")
#define BARX do { asm volatile("" ::: "memory"); __builtin_amdgcn_sched_barrier(0); \
                  __builtin_amdgcn_s_barrier(); \
                  __builtin_amdgcn_sched_barrier(0); asm volatile("" ::: "memory"); } while (0)

#define LD16SYS(d, a, O) asm volatile("global_load_dwordx4 %0, %1, off offset:" #O " sc0 sc1" : "=v"(d) : "v"(a) : "memory")
#define ST8SYS(a, v)     asm volatile("global_store_dwordx2 %0, %1, off sc0 sc1" :: "v"(a), "v"(v) : "memory")
#define STFLAG(a, v)     asm volatile("global_store_dword %0, %1, off sc0 sc1" :: "v"(a), "v"(v) : "memory")
#define LDFLAGS(d0, d1, a) asm volatile("global_load_dwordx4 %0, %2, off sc0 sc1\n\t" \
                                        "global_load_dwordx4 %1, %2, off offset:16 sc0 sc1" \
                                        : "=v"(d0), "=v"(d1) : "v"(a) : "memory")
#define LDX8(d, a)       asm volatile("global_load_dwordx2 %0, %1, off" : "=v"(d) : "v"(a) : "memory")

// LDS: slab [16][2064] @0 (33024 B); hvbuf 2 x 8192 @33024. total 49408.
__global__ __launch_bounds__(576) void k_scan(const float* __restrict__ Whh,
                                              const unsigned short* __restrict__ Xp,
                                              unsigned short* __restrict__ hbuf, // [4][2 par][16][1024] bf16
                                              unsigned int* flags,               // [4][8 slice][8 wave] u32
                                              float* __restrict__ out) {
    __shared__ __align__(16) unsigned char lds[49408];
    const int wgid = blockIdx.x;          // 0..15
    const int set = wgid & 1, s = wgid >> 1;
    const int c0 = set * 2, c1 = set * 2 + 1;
    const int tid = threadIdx.x;
    const int lane = tid & 63, wid = tid >> 6;

    if (wid < 8) {
        // ========================= compute wave ==============================
        const int l15 = lane & 15, kg = lane >> 4;
        const int jt = s * 128 + wid * 16;
        const int jl = jt + kg * 4;

        bf16x8 w[32];
#pragma unroll
        for (int i = 0; i < 32; ++i)
#pragma unroll
            for (int e = 0; e < 8; ++e)
                w[i][e] = (short)bf16_rne(Whh[(size_t)(i * 32 + kg * 8 + e) * 1024 + jt + l15]);

        const uint64_t crd0 = (uint64_t)hbuf + (uint64_t)c0 * 65536 +
                              (uint64_t)(lane >> 2) * 2048 + wid * 256 + (lane & 3) * 64;
        const uint64_t crd1 = crd0 + 65536;
        unsigned char* ldsw = lds + (lane >> 2) * 2064 + wid * 256 + (lane & 3) * 64;
        const unsigned char* lrd = lds + l15 * 2064 + kg * 16;
        const uint64_t hwr0 = (uint64_t)hbuf + (uint64_t)c0 * 65536 +
                              (uint64_t)l15 * 2048 + (uint64_t)jl * 2;
        const uint64_t hwr1 = hwr0 + 65536;
        const uint64_t fp0 = (uint64_t)flags + (uint64_t)c0 * 256 + wid * 32;  // poll producer=wid
        const uint64_t fp1 = fp0 + 256;
        const uint64_t mf0 = (uint64_t)flags + (uint64_t)c0 * 256 + s * 32 + wid * 4;
        const uint64_t mf1 = mf0 + 256;
        const uint64_t xpb0 = (uint64_t)Xp + ((uint64_t)(c0 * 16 + l15) * 1024 + jl) * 2;
        const uint64_t xpb1 = xpb0 + 32768;   // +16 rows * 2048 B

        // prologue: xp(r=0) both chains; slab (c0, r=0)
        u32x2 xr0, xr1, xtmp;
        LDX8(xr0, xpb0); LDX8(xr1, xpb1);
        u32x4 sq0, sq1, sq2, sq3;
        LD16SYS(sq0, crd0, 0); LD16SYS(sq1, crd0, 16);
        LD16SYS(sq2, crd0, 32); LD16SYS(sq3, crd0, 48);
        WV0; SB0;

        f32x4 hvs0 = {0.f, 0.f, 0.f, 0.f}, hvs1 = {0.f, 0.f, 0.f, 0.f};

        for (int p = 0; p < 1024; ++p) {
            const int r = p >> 1, cl = p & 1;
            const int rn = (p + 1) >> 1, cln = (p + 1) & 1;
            // step 0: prefetch next-phase flags (2 x dwordx4, producer wid's 8 wave-flags)
            u32x4 f0, f1;
            if (p < 1023) {
                uint64_t fp = cln ? fp1 : fp0;
                LDFLAGS(f0, f1, fp);
            }
            // step 1: publish slab regs to LDS
            *(u32x4*)(ldsw)      = sq0; *(u32x4*)(ldsw + 16) = sq1;
            *(u32x4*)(ldsw + 32) = sq2; *(u32x4*)(ldsw + 48) = sq3;
            WLG0;
            BARX;   // A: slab(c, r) in LDS
            // step 3: check flags; repoll if stale (bounded)
            if (p < 1023) {
                WV0; SB0;
                unsigned rt = (unsigned)rn;
                int ok = (f0[0] >= rt) && (f0[1] >= rt) && (f0[2] >= rt) && (f0[3] >= rt) &&
                         (f1[0] >= rt) && (f1[1] >= rt) && (f1[2] >= rt) && (f1[3] >= rt);
                unsigned it = 0;
                while (!__all(ok) && it < (1u << 20)) {
                    uint64_t fp = cln ? fp1 : fp0;
                    LDFLAGS(f0, f1, fp);
                    WV0; SB0;
                    ok = (f0[0] >= rt) && (f0[1] >= rt) && (f0[2] >= rt) && (f0[3] >= rt) &&
                         (f1[0] >= rt) && (f1[1] >= rt) && (f1[2] >= rt) && (f1[3] >= rt);
                    ++it;
                }
                // step 4: issue next slab loads (chain cn, step rn, parity rn&1)
                uint64_t ca = (cln ? crd1 : crd0) + ((uint64_t)(rn & 1) << 15);
                LD16SYS(sq0, ca, 0); LD16SYS(sq1, ca, 16);
                LD16SYS(sq2, ca, 32); LD16SYS(sq3, ca, 48);
                // step 5: issue xp for (c, r+1)
                if (r < 511) LDX8(xtmp, (cl ? xpb1 : xpb0) + (uint64_t)(r + 1) * 131072);
            }
            // step 6: MFMA (chain c, step r) from LDS
            f32x4 a0 = {0.f, 0.f, 0.f, 0.f}, a1 = {0.f, 0.f, 0.f, 0.f};
            f32x4 a2 = {0.f, 0.f, 0.f, 0.f}, a3 = {0.f, 0.f, 0.f, 0.f};
#pragma unroll
            for (int ks = 0; ks < 8; ++ks) {
                a0 = __builtin_amdgcn_mfma_f32_16x16x32_bf16(
                    w[4 * ks + 0], *(const bf16x8*)(lrd + (4 * ks + 0) * 64), a0, 0, 0, 0);
                a1 = __builtin_amdgcn_mfma_f32_16x16x32_bf16(
                    w[4 * ks + 1], *(const bf16x8*)(lrd + (4 * ks + 1) * 64), a1, 0, 0, 0);
                a2 = __builtin_amdgcn_mfma_f32_16x16x32_bf16(
                    w[4 * ks + 2], *(const bf16x8*)(lrd + (4 * ks + 2) * 64), a2, 0, 0, 0);
                a3 = __builtin_amdgcn_mfma_f32_16x16x32_bf16(
                    w[4 * ks + 3], *(const bf16x8*)(lrd + (4 * ks + 3) * 64), a3, 0, 0, 0);
            }
            f32x4 acc = (a0 + a1) + (a2 + a3);
            BARX;   // B: all waves done reading LDS slab
            // step 8: tanh
            u32x2 xr = cl ? xr1 : xr0;
            float xpf[4] = { bf16tof((unsigned short)(xr[0] & 0xffffu)),
                             bf16tof((unsigned short)(xr[0] >> 16)),
                             bf16tof((unsigned short)(xr[1] & 0xffffu)),
                             bf16tof((unsigned short)(xr[1] >> 16)) };
            f32x4 hv;
            unsigned hb16[4];
#pragma unroll
            for (int q = 0; q < 4; ++q) {
                float z = acc[q] + xpf[q];
                z = fminf(fmaxf(z, -15.f), 15.f);
                float e = __expf(2.f * z);
                float v = (e - 1.f) / (e + 1.f);
                hv[q] = v;
                hb16[q] = (unsigned)bf16_rne(v);
            }
            // step 9: hand off hv to helper
            *(f32x4*)(lds + 33024 + (p & 1) * 8192 + tid * 16) = hv;
            // step 10-13: publish h, ack, flag
            if (r < 511) {
                u32x2 hh = { hb16[0] | (hb16[1] << 16), hb16[2] | (hb16[3] << 16) };
                ST8SYS((cl ? hwr1 : hwr0) + ((uint64_t)((r + 1) & 1) << 15), hh);
            }
            WV0; SB0;
            if (p < 1023 && r < 511) { if (cl) xr1 = xtmp; else xr0 = xtmp; }
            if (r < 511 && lane == 0)
                STFLAG(cl ? mf1 : mf0, (unsigned)(r + 1));
            if (r == 511) { if (cl) hvs1 = hv; else hvs0 = hv; }
        }
        BARX;   // epilogue A (helper flushes last hvbuf)
        *(f32x4*)((float*)out + (size_t)33554432 + (size_t)(c0 * 16 + l15) * 1024 + jl) = hvs0;
        *(f32x4*)((float*)out + (size_t)33554432 + (size_t)(c1 * 16 + l15) * 1024 + jl) = hvs1;
    } else {
        // ========================= helper wave (out drain) ====================
        for (int p = 0; p < 1024; ++p) {
            BARX;   // A
            if (p > 0) {
                const int pm = p - 1, pr = pm >> 1, pcl = pm & 1;
                const int pc = set * 2 + pcl;
#pragma unroll
                for (int k = 0; k < 8; ++k) {
                    f32x4 v = *(const f32x4*)(lds + 33024 + (pm & 1) * 8192 + (k * 64 + lane) * 16);
                    *(f32x4*)((float*)out + ((size_t)(pr * 64 + pc * 16 + (lane & 15)) * 1024 +
                                             s * 128 + k * 16 + (lane >> 4) * 4)) = v;
                }
            }
            BARX;   // B
        }
        BARX;   // epilogue A: flush p=1023 (chain set*2+1, r=511)
        {
            const int pc = set * 2 + 1;
#pragma unroll
            for (int k = 0; k < 8; ++k) {
                f32x4 v = *(const f32x4*)(lds + 33024 + 8192 + (k * 64 + lane) * 16);
                *(f32x4*)((float*)out + ((size_t)(511 * 64 + pc * 16 + (lane & 15)) * 1024 +
                                         s * 128 + k * 16 + (lane >> 4) * 4)) = v;
            }
        }
    }
}

// ---------------- launcher ---------------------------------------------------
extern "C" void kernel_launch(void* const* d_in, const int* in_sizes, int n_in,
                              void* d_out, int out_size, void* d_ws, size_t ws_size,
                              hipStream_t stream) {
    const float* X   = (const float*)d_in[0];
    const float* Wxh = (const float*)d_in[1];
    const float* Whh = (const float*)d_in[2];
    const float* bh  = (const float*)d_in[3];
    float* out = (float*)d_out;
    unsigned char* ws = (unsigned char*)d_ws;

    // workspace layout (bytes), high-water 69,469,184 (round-2-proven):
    //   [0)         Wt    : 2 MB    (W_xh^T bf16)
    //   [2097152)   Xp    : 64 MB   (bf16 [T*B][H])
    //   [69206016)  hbuf  : 256 KB  (bf16 [4 chain][2 par][16 b][1024 k])
    //   [69468160)  flags : 1 KB    ([4][8 slice][8 wave] u32)
    unsigned short* Wt    = (unsigned short*)(ws);
    unsigned short* Xp    = (unsigned short*)(ws + 2097152);
    unsigned short* hbuf  = (unsigned short*)(ws + 69206016);
    unsigned int*   flags = (unsigned int*)(ws + 69468160);

    hipMemsetAsync(ws + 69206016, 0, 263168, stream);   // hbuf + flags
    hipLaunchKernelGGL(k_transpose, dim3(256), dim3(256), 0, stream, Wxh, Wt);
    hipLaunchKernelGGL(k_xpgemm, dim3(2048), dim3(256), 0, stream, X, Wt, bh, Xp);
    hipLaunchKernelGGL(k_scan, dim3(16), dim3(576), 0, stream, Whh, Xp, hbuf, flags, out);
}